// Round 5
// baseline (401.529 us; speedup 1.0000x reference)
//
#include <hip/hip_runtime.h>

#define LOG2E 1.44269504088896340736f

typedef _Float16 f16_t;
typedef f16_t f16x8 __attribute__((ext_vector_type(8)));
typedef f16_t f16x4 __attribute__((ext_vector_type(4)));
typedef float f32x4 __attribute__((ext_vector_type(4)));

// Problem constants: N=4096 nodes, F_in=512, F_out=128, H=8 heads.

// ---- K0a: pack adjacency (int32 0/1, 64MB) into bitmask (2MB) ----
__global__ __launch_bounds__(256) void k_pack_adj(const int* __restrict__ adj,
                                                  unsigned char* __restrict__ mask8) {
  const int t = blockIdx.x * 256 + threadIdx.x;  // 2M threads
  const int4 a = ((const int4*)adj)[t * 2];
  const int4 b = ((const int4*)adj)[t * 2 + 1];
  unsigned v = (a.x > 0) | ((a.y > 0) << 1) | ((a.z > 0) << 2) | ((a.w > 0) << 3) |
               ((b.x > 0) << 4) | ((b.y > 0) << 5) | ((b.z > 0) << 6) | ((b.w > 0) << 7);
  mask8[t] = (unsigned char)v;
}

// ---- K0b: x fp32 -> fp16 ----
__global__ __launch_bounds__(256) void k_cvt_x(const float* __restrict__ x,
                                               f16_t* __restrict__ xh) {
  const int t = blockIdx.x * 256 + threadIdx.x;
  const f32x4 a = ((const f32x4*)x)[t * 2];
  const f32x4 b = ((const f32x4*)x)[t * 2 + 1];
  f16x8 o;
#pragma unroll
  for (int i = 0; i < 4; ++i) { o[i] = (f16_t)a[i]; o[i + 4] = (f16_t)b[i]; }
  ((f16x8*)xh)[t] = o;
}

// ---- K0c: W [h][k][o] fp32 -> WT [h][o][k] fp16 ----
__global__ __launch_bounds__(256) void k_cvt_w(const float* __restrict__ W,
                                               f16_t* __restrict__ WT) {
  const int t = blockIdx.x * 256 + threadIdx.x;  // 524288
  const int k = t & 511, o = (t >> 9) & 127, h = t >> 16;
  WT[t] = (f16_t)W[((h << 9) + k) * 128 + o];
}

// ---- K1: Wh = x@W per head (fp16 MFMA). Store WhB pre-swizzled in PV
// B-fragment order; epilogue computes piecewise-exp tables
// EA=2^(fs*L), EA2=2^(0.2*fs*L), EB=2^(fd*L), EB2=2^(0.2*fd*L) as fp16.
__global__ __launch_bounds__(256) void k_gemm_wh(const f16_t* __restrict__ xh,
                                                 const f16_t* __restrict__ WT,
                                                 const float* __restrict__ a_src,
                                                 const float* __restrict__ a_dst,
                                                 f16_t* __restrict__ WhB,
                                                 f16_t* __restrict__ EA,
                                                 f16_t* __restrict__ EA2,
                                                 f16_t* __restrict__ EB,
                                                 f16_t* __restrict__ EB2) {
  const int h = blockIdx.y;
  const int n0 = blockIdx.x * 64;
  const int lane = threadIdx.x & 63;
  const int w = threadIdx.x >> 6;
  const int col = lane & 15;
  const int kg = lane >> 4;
  const f16_t* xrow = xh + (size_t)(n0 + w * 16 + col) * 512 + kg * 8;
  const f16_t* wb = WT + ((size_t)h << 16) + (size_t)col * 512 + kg * 8;
  f32x4 acc[8] = {};
  for (int kk = 0; kk < 512; kk += 32) {
    const f16x8 a = *(const f16x8*)(xrow + kk);
#pragma unroll
    for (int ot = 0; ot < 8; ++ot) {
      const f16x8 b = *(const f16x8*)(wb + ot * (16 * 512) + kk);
      acc[ot] = __builtin_amdgcn_mfma_f32_16x16x32_f16(a, b, acc[ot], 0, 0, 0);
    }
  }
  float ps[4] = {0.f, 0.f, 0.f, 0.f}, pd[4] = {0.f, 0.f, 0.f, 0.f};
#pragma unroll
  for (int ot = 0; ot < 8; ++ot) {
    const float as = a_src[h * 128 + ot * 16 + col];
    const float ad = a_dst[h * 128 + ot * 16 + col];
#pragma unroll
    for (int r = 0; r < 4; ++r) { ps[r] += acc[ot][r] * as; pd[r] += acc[ot][r] * ad; }
  }
#pragma unroll
  for (int m = 1; m < 16; m <<= 1) {
#pragma unroll
    for (int r = 0; r < 4; ++r) {
      ps[r] += __shfl_xor(ps[r], m, 64);
      pd[r] += __shfl_xor(pd[r], m, 64);
    }
  }
  const int nb = n0 + w * 16 + kg * 4;  // node index of acc[.][0]
  if (col == 0) {
#pragma unroll
    for (int r = 0; r < 4; ++r) {
      const float fs = ps[r] * LOG2E;
      const float fd = pd[r] * LOG2E;
      const int idx = h * 4096 + nb + r;
      EA[idx] = (f16_t)__builtin_amdgcn_exp2f(fs);
      EA2[idx] = (f16_t)__builtin_amdgcn_exp2f(0.2f * fs);
      EB[idx] = (f16_t)__builtin_amdgcn_exp2f(fd);
      EB2[idx] = (f16_t)__builtin_amdgcn_exp2f(0.2f * fd);
    }
  }
  // swizzled store: (h,o,j) -> WhB[((h*128+j/32)*8+o/16)*512 + ((j>>3)&3)*128 + (o&15)*8 + (j&7)]
  const int jb = nb >> 5;
  const int kgt = (nb >> 3) & 3;
  const int e0 = nb & 4;
  const size_t base = ((size_t)(h * 128 + jb) * 8) * 512 + kgt * 128 + col * 8 + e0;
#pragma unroll
  for (int ot = 0; ot < 8; ++ot) {
    f16x4 v;
#pragma unroll
    for (int r = 0; r < 4; ++r) v[r] = (f16_t)acc[ot][r];
    *(f16x4*)(WhB + base + ot * 512) = v;
  }
}

// ---- K2: masked softmax + PV, direct output ----
// grid = 2048 (bx&7 = head -> XCD; bx>>3 = 16-row i-tile). Block 4 waves;
// wave w owns j in [w*1024, w*1024+1024) (32 j-blocks of 32). Cross-wave
// merge via LDS in two o-halves. p = max(EA_i*EB_j, EA2_i*EB2_j) * m_ij.
__global__ __launch_bounds__(256, 6) void k_pv(const f16_t* __restrict__ WhB,
                                               const f16_t* __restrict__ EA,
                                               const f16_t* __restrict__ EA2,
                                               const f16_t* __restrict__ EB,
                                               const f16_t* __restrict__ EB2,
                                               const unsigned char* __restrict__ mask,
                                               float* __restrict__ out) {
  __shared__ __align__(16) unsigned short lut[256][8];
  __shared__ float lds_acc[4][16][68];  // pad 64->68: kg-stores 2-way (free)
  __shared__ float lds_den[4][16];
  {
    const int t = threadIdx.x;
#pragma unroll
    for (int e = 0; e < 8; ++e) lut[t][e] = ((t >> e) & 1) ? 0x3C00 : 0;
  }
  __syncthreads();
  const int bx = blockIdx.x;
  const int h = bx & 7;                 // head -> XCD round-robin
  const int rbase = (bx >> 3) << 4;     // 16-row i-tile
  const int lane = threadIdx.x & 63;
  const int w = threadIdx.x >> 6;
  const int col = lane & 15, kg = lane >> 4;
  const int row0 = rbase + col;
  const int sh = kg * 8;
  f16x8 A0s, A20s, ones;
  {
    const f16_t A0 = EA[h * 4096 + row0], A20 = EA2[h * 4096 + row0];
#pragma unroll
    for (int e = 0; e < 8; ++e) { A0s[e] = A0; A20s[e] = A20; ones[e] = (f16_t)1.0f; }
  }
  const unsigned char* m0 = mask + (size_t)row0 * 512 + w * 128;
  const f16_t* EBp = EB + h * 4096 + w * 1024 + kg * 8;
  const f16_t* EB2p = EB2 + h * 4096 + w * 1024 + kg * 8;
  const f16_t* whB = WhB + ((size_t)h << 19) + ((size_t)w << 17) + lane * 8;
  f32x4 acc[8] = {};
  f32x4 den = {};
  for (int g = 0; g < 8; ++g) {
    const uint4 md = *(const uint4*)(m0 + g * 16);
#pragma unroll
    for (int q = 0; q < 4; ++q) {
      const int itb = g * 4 + q;
      const f16x8 vb = *(const f16x8*)(EBp + itb * 32);
      const f16x8 vb2 = *(const f16x8*)(EB2p + itb * 32);
      const unsigned mw = (q == 0) ? md.x : (q == 1) ? md.y : (q == 2) ? md.z : md.w;
      const unsigned mb = (mw >> sh) & 255u;
      const f16x8 lm = *(const f16x8*)(&lut[mb][0]);
      const f16x8 a = __builtin_elementwise_max(A0s * vb, A20s * vb2) * lm;
      den = __builtin_amdgcn_mfma_f32_16x16x32_f16(a, ones, den, 0, 0, 0);
      const f16_t* wp = whB + (size_t)itb * 4096;
#pragma unroll
      for (int ot = 0; ot < 8; ++ot) {
        const f16x8 b = *(const f16x8*)(wp + ot * 512);
        acc[ot] = __builtin_amdgcn_mfma_f32_16x16x32_f16(a, b, acc[ot], 0, 0, 0);
      }
    }
  }
  // den partials (row = kg*4+r lives on col==0 lanes' D frag)
  if (col == 0) {
#pragma unroll
    for (int r = 0; r < 4; ++r) lds_den[w][kg * 4 + r] = den[r];
  }
  // two-round cross-wave merge over o-halves
#pragma unroll
  for (int rnd = 0; rnd < 2; ++rnd) {
    __syncthreads();  // guard vs previous round's reads (and den write visibility)
#pragma unroll
    for (int ot4 = 0; ot4 < 4; ++ot4) {
#pragma unroll
      for (int r = 0; r < 4; ++r) {
        lds_acc[w][kg * 4 + r][ot4 * 16 + col] = acc[rnd * 4 + ot4][r];
      }
    }
    __syncthreads();
    const int row = threadIdx.x >> 4;
    const int ob = (threadIdx.x & 15) * 4;
    f32x4 s = *(const f32x4*)(&lds_acc[0][row][ob]);
    s += *(const f32x4*)(&lds_acc[1][row][ob]);
    s += *(const f32x4*)(&lds_acc[2][row][ob]);
    s += *(const f32x4*)(&lds_acc[3][row][ob]);
    const float dsum = lds_den[0][row] + lds_den[1][row] + lds_den[2][row] + lds_den[3][row];
    const float inv = __builtin_amdgcn_rcpf(dsum);
    f32x4 o;
#pragma unroll
    for (int i = 0; i < 4; ++i) o[i] = s[i] * inv;
    *(f32x4*)(out + (size_t)(rbase + row) * 1024 + h * 128 + rnd * 64 + ob) = o;
  }
}

extern "C" void kernel_launch(void* const* d_in, const int* in_sizes, int n_in,
                              void* d_out, int out_size, void* d_ws, size_t ws_size,
                              hipStream_t stream) {
  const float* x = (const float*)d_in[0];
  const int* adj = (const int*)d_in[1];
  const float* W = (const float*)d_in[2];
  const float* a_src = (const float*)d_in[3];
  const float* a_dst = (const float*)d_in[4];
  float* out = (float*)d_out;
  char* ws = (char*)d_ws;
  // workspace layout (bytes):
  //   WhB   swizzled f16          : 0        .. 8388608
  //   xh    [4096][512] f16       : 8388608  .. 12582912
  //   WT    [8][128][512] f16     : 12582912 .. 13631488
  //   mask  [4096][512] u8        : 13631488 .. 15728640
  //   EA/EA2/EB/EB2 [8][4096] f16 : 15728640 .. 15990784 (4 x 64KB)
  f16_t* WhB = (f16_t*)(ws);
  f16_t* xh = (f16_t*)(ws + 8388608);
  f16_t* WT = (f16_t*)(ws + 12582912);
  unsigned char* mask8 = (unsigned char*)(ws + 13631488);
  f16_t* EA = (f16_t*)(ws + 15728640);
  f16_t* EA2 = (f16_t*)(ws + 15794176);
  f16_t* EB = (f16_t*)(ws + 15859712);
  f16_t* EB2 = (f16_t*)(ws + 15925248);

  k_pack_adj<<<8192, 256, 0, stream>>>(adj, mask8);
  k_cvt_x<<<1024, 256, 0, stream>>>(x, xh);
  k_cvt_w<<<2048, 256, 0, stream>>>(W, WT);
  k_gemm_wh<<<dim3(64, 8), 256, 0, stream>>>(xh, WT, a_src, a_dst, WhB, EA, EA2, EB, EB2);
  k_pv<<<2048, 256, 0, stream>>>(WhB, EA, EA2, EB, EB2, mask8, out);
}